// Round 11
// baseline (168.266 us; speedup 1.0000x reference)
//
#include <hip/hip_runtime.h>
#include <math.h>

#define HD    128
#define NQH   32
#define NKVH  8
#define GQA   4
#define PBLK  16
#define MAXNB 512
#define CHUNK 64       // tokens per staged chunk (32KB K + 32KB V per buffer)

#define L2_10000 13.287712379549449f   // log2(10000)

typedef float f4 __attribute__((ext_vector_type(4)));

// raw barrier: waits LDS ops only, does NOT drain vmcnt -> the async stage of
// the next chunk stays in flight across the softmax barriers (T4 principle).
__device__ __forceinline__ void bar_lds() {
    asm volatile("s_waitcnt lgkmcnt(0)\n\ts_barrier" ::: "memory");
}

__global__ __launch_bounds__(512) void paged_attn_kernel(
    const float* __restrict__ q,
    const float* __restrict__ kcur,
    const float* __restrict__ vcur,
    const float* __restrict__ kc,
    const float* __restrict__ vc,
    const int* __restrict__ bt,
    float* __restrict__ out,
    int T, int nb)
{
    const int b   = blockIdx.x >> 3;
    const int h   = blockIdx.x & 7;
    const int tid = threadIdx.x;
    const int L   = tid & 63;
    const int w   = tid >> 6;       // wave 0..7
    const int il  = tid & 31;
    const int hw  = tid >> 5;       // half-wave 0..15 (PV)
    const int d0v = il << 2;
    const int tk8 = tid >> 3;       // dot: token 0..63
    const int p8  = tid & 7;        // dot: freq octet (freqs p8*8..p8*8+8)
    const int tt4 = tid >> 2;       // softmax: token
    const int j4  = tid & 3;        // softmax: head

    __shared__ float Kt[2][CHUNK * HD];   // 2 x 32KB, linear [token][d]
    __shared__ float Vt[2][CHUNK * HD];   // 2 x 32KB
    __shared__ float sc[CHUNK * 4];       // scores/p [token][g]
    __shared__ float qsm[4 * HD];         // roped+scaled q
    __shared__ float redM[8][4], redL[8][4];
    __shared__ int   sbt[MAXNB];

    const int* btrow0 = bt + (size_t)b * nb;
    if (nb <= MAXNB) for (int i = tid; i < nb; i += 512) sbt[i] = btrow0[i];
    if (tid < 256) {                      // rope current q, fold in 1/sqrt(128)
        const int g = tid >> 6, f = tid & 63;
        const float* qb = q + ((size_t)b * NQH + h * GQA + g) * HD;
        float xlo = qb[f], xhi = qb[64 + f];
        float invf = exp2f(-(float)f * (L2_10000 / 64.0f));
        float ss, cc;
        sincosf((float)T * invf, &ss, &cc);
        const float scale = 0.08838834764831845f;
        qsm[g * HD + f]      = (xlo * cc - xhi * ss) * scale;
        qsm[g * HD + 64 + f] = (xhi * cc + xlo * ss) * scale;
    }
    __syncthreads();                      // sbt/qsm visible before staging
    const int* btrow = (nb <= MAXNB) ? sbt : btrow0;

    const float* kcurp = kcur + ((size_t)b * NKVH + h) * HD;
    const float* vcurp = vcur + ((size_t)b * NKVH + h) * HD;

    const int total = T + 1;
    const int nc = (total + CHUNK - 1) / CHUNK;

    // rope phase state: this thread's 8 freqs at token tk8; advance CHUNK/chunk
    float pc[8], ps[8], rc[8], rs[8];
#pragma unroll
    for (int j = 0; j < 8; ++j) {
        float invf = exp2f(-(float)(p8 * 8 + j) * (L2_10000 / 64.0f));
        sincosf((float)tk8 * invf, &ps[j], &pc[j]);
        sincosf((float)CHUNK * invf, &rs[j], &rc[j]);
    }

    float Mr0 = -INFINITY, Mr1 = -INFINITY, Mr2 = -INFINITY, Mr3 = -INFINITY;
    float Lr0 = 0.f, Lr1 = 0.f, Lr2 = 0.f, Lr3 = 0.f;
    f4 o0 = {0,0,0,0}, o1 = {0,0,0,0}, o2 = {0,0,0,0}, o3 = {0,0,0,0};

    auto STAGE = [&](int c, int bb) {
#pragma unroll
        for (int j = 0; j < 4; ++j) {
            int off = w * 4096 + j * 1024 + L * 16;   // byte offset in 32KB tile
            int tok = c * CHUNK + (off >> 9);
            int ro  = off & 511;
            int tc  = min(tok, T);                    // clamp tail to a valid row
            const float *kb, *vb;
            if (tc == T) { kb = kcurp; vb = vcurp; }
            else {
                int blk = btrow[tc >> 4];
                size_t boff = (((size_t)blk * PBLK + (tc & 15)) * NKVH + h) * HD;
                kb = kc + boff; vb = vc + boff;
            }
            // dest = wave-uniform base; HW adds lane*16 (linear -> matches off)
            __builtin_amdgcn_global_load_lds(
                (const __attribute__((address_space(1))) void*)((const char*)kb + ro),
                (__attribute__((address_space(3))) void*)((char*)&Kt[bb][0] + w * 4096 + j * 1024),
                16, 0, 0);
            __builtin_amdgcn_global_load_lds(
                (const __attribute__((address_space(1))) void*)((const char*)vb + ro),
                (__attribute__((address_space(3))) void*)((char*)&Vt[bb][0] + w * 4096 + j * 1024),
                16, 0, 0);
        }
    };

    int cur = 0;
    STAGE(0, 0);

    for (int c = 0; c < nc; ++c) {
        __syncthreads();                  // A: vmcnt auto-drained -> stage(c) done
        if (c + 1 < nc) STAGE(c + 1, cur ^ 1);   // in flight across whole chunk

        const int clo = c * CHUNK;
        const int cn  = min(CHUNK, total - clo);

        // ---- rope+dot, fully in-lane: thread = (token, freq-octet) ----
        float a0, a1, a2, a3;
        {
            const float* Kb = &Kt[cur][tk8 * HD + p8 * 8];
            f4 klo0 = *(const f4*)(Kb);
            f4 klo1 = *(const f4*)(Kb + 4);
            f4 khi0 = *(const f4*)(Kb + 64);
            f4 khi1 = *(const f4*)(Kb + 68);
            float krl[8], krh[8];
#pragma unroll
            for (int j = 0; j < 8; ++j) {
                float kl = (j < 4) ? klo0[j] : klo1[j - 4];
                float kh = (j < 4) ? khi0[j] : khi1[j - 4];
                krl[j] = kl * pc[j] - kh * ps[j];
                krh[j] = kh * pc[j] + kl * ps[j];
            }
#pragma unroll
            for (int j = 0; j < 8; ++j) {  // advance phase by CHUNK positions
                float nc_ = pc[j] * rc[j] - ps[j] * rs[j];
                float ns_ = ps[j] * rc[j] + pc[j] * rs[j];
                pc[j] = nc_; ps[j] = ns_;
            }
            a0 = a1 = a2 = a3 = 0.f;
#pragma unroll
            for (int g = 0; g < 4; ++g) {
                const float* Qb = &qsm[g * HD + p8 * 8];
                f4 ql0 = *(const f4*)(Qb);
                f4 ql1 = *(const f4*)(Qb + 4);
                f4 qh0 = *(const f4*)(Qb + 64);
                f4 qh1 = *(const f4*)(Qb + 68);
                float s = 0.f;
#pragma unroll
                for (int j = 0; j < 8; ++j) {
                    float ql = (j < 4) ? ql0[j] : ql1[j - 4];
                    float qh = (j < 4) ? qh0[j] : qh1[j - 4];
                    s += ql * krl[j] + qh * krh[j];
                }
                if (g == 0) a0 = s; else if (g == 1) a1 = s;
                else if (g == 2) a2 = s; else a3 = s;
            }
        }
        a0 += __shfl_xor(a0, 1); a0 += __shfl_xor(a0, 2); a0 += __shfl_xor(a0, 4);
        a1 += __shfl_xor(a1, 1); a1 += __shfl_xor(a1, 2); a1 += __shfl_xor(a1, 4);
        a2 += __shfl_xor(a2, 1); a2 += __shfl_xor(a2, 2); a2 += __shfl_xor(a2, 4);
        a3 += __shfl_xor(a3, 1); a3 += __shfl_xor(a3, 2); a3 += __shfl_xor(a3, 4);
        if (p8 < 4 && tk8 < cn) {
            float av = (p8 == 0) ? a0 : (p8 == 1) ? a1 : (p8 == 2) ? a2 : a3;
            sc[tk8 * 4 + p8] = av;
        }
        bar_lds();                        // D (no vmcnt drain)

        // ---- block softmax over the chunk ----
        float sv = (tt4 < cn) ? sc[tt4 * 4 + j4] : -INFINITY;
        float pmax = sv;
        pmax = fmaxf(pmax, __shfl_xor(pmax, 4));
        pmax = fmaxf(pmax, __shfl_xor(pmax, 8));
        pmax = fmaxf(pmax, __shfl_xor(pmax, 16));
        pmax = fmaxf(pmax, __shfl_xor(pmax, 32));
        if ((tid & 63) < 4) redM[w][tid & 3] = pmax;
        bar_lds();                        // F

        float Mn0 = Mr0, Mn1 = Mr1, Mn2 = Mr2, Mn3 = Mr3;
#pragma unroll
        for (int i = 0; i < 8; ++i) {
            Mn0 = fmaxf(Mn0, redM[i][0]); Mn1 = fmaxf(Mn1, redM[i][1]);
            Mn2 = fmaxf(Mn2, redM[i][2]); Mn3 = fmaxf(Mn3, redM[i][3]);
        }
        float Mg = (j4 == 0) ? Mn0 : (j4 == 1) ? Mn1 : (j4 == 2) ? Mn2 : Mn3;
        float lsum = 0.f;
        if (tt4 < cn) {
            float p = __expf(sv - Mg);
            sc[tt4 * 4 + j4] = p;         // own slot: no cross-thread hazard
            lsum = p;
        }
        lsum += __shfl_xor(lsum, 4);
        lsum += __shfl_xor(lsum, 8);
        lsum += __shfl_xor(lsum, 16);
        lsum += __shfl_xor(lsum, 32);
        if ((tid & 63) < 4) redL[w][tid & 3] = lsum;
        bar_lds();                        // H

        {
            float Lc0 = 0.f, Lc1 = 0.f, Lc2 = 0.f, Lc3 = 0.f;
#pragma unroll
            for (int i = 0; i < 8; ++i) {
                Lc0 += redL[i][0]; Lc1 += redL[i][1];
                Lc2 += redL[i][2]; Lc3 += redL[i][3];
            }
            float e0 = __expf(Mr0 - Mn0);   // first chunk: exp(-inf) = 0
            float e1 = __expf(Mr1 - Mn1);
            float e2 = __expf(Mr2 - Mn2);
            float e3 = __expf(Mr3 - Mn3);
            Lr0 = Lr0 * e0 + Lc0; o0 *= e0; Mr0 = Mn0;
            Lr1 = Lr1 * e1 + Lc1; o1 *= e1; Mr1 = Mn1;
            Lr2 = Lr2 * e2 + Lc2; o2 *= e2; Mr2 = Mn2;
            Lr3 = Lr3 * e3 + Lc3; o3 *= e3; Mr3 = Mn3;
        }

        // ---- PV from LDS (token per half-wave, p broadcast) ----
#pragma unroll
        for (int it = 0; it < 4; ++it) {
            int tt = hw + 16 * it;
            if (tt < cn) {
                f4 pv = *(const f4*)&sc[tt * 4];
                f4 vv = *(const f4*)&Vt[cur][tt * HD + d0v];
                o0 += pv.x * vv; o1 += pv.y * vv;
                o2 += pv.z * vv; o3 += pv.w * vv;
            }
        }
        cur ^= 1;
    }

    __syncthreads();   // all chunk work done; safe to alias Kt as scratch

    // half-wave pair combine (lanes il and il+32 hold the same dims)
    o0.x += __shfl_xor(o0.x, 32); o0.y += __shfl_xor(o0.y, 32);
    o0.z += __shfl_xor(o0.z, 32); o0.w += __shfl_xor(o0.w, 32);
    o1.x += __shfl_xor(o1.x, 32); o1.y += __shfl_xor(o1.y, 32);
    o1.z += __shfl_xor(o1.z, 32); o1.w += __shfl_xor(o1.w, 32);
    o2.x += __shfl_xor(o2.x, 32); o2.y += __shfl_xor(o2.y, 32);
    o2.z += __shfl_xor(o2.z, 32); o2.w += __shfl_xor(o2.w, 32);
    o3.x += __shfl_xor(o3.x, 32); o3.y += __shfl_xor(o3.y, 32);
    o3.z += __shfl_xor(o3.z, 32); o3.w += __shfl_xor(o3.w, 32);

    float* lod = &Kt[0][0];   // [8 waves][4 g][HD] = 16KB scratch
    if ((tid & 32) == 0) {
        *(f4*)&lod[(w * 4 + 0) * HD + d0v] = o0;
        *(f4*)&lod[(w * 4 + 1) * HD + d0v] = o1;
        *(f4*)&lod[(w * 4 + 2) * HD + d0v] = o2;
        *(f4*)&lod[(w * 4 + 3) * HD + d0v] = o3;
    }
    __syncthreads();
    {
        const int g = tid >> 7;          // 512 threads = 4 heads x 128 dims
        const int d = tid & 127;
        float O = 0.f;
#pragma unroll
        for (int i = 0; i < 8; ++i) O += lod[(i * 4 + g) * HD + d];
        float Lsel = (g == 0) ? Lr0 : (g == 1) ? Lr1 : (g == 2) ? Lr2 : Lr3;
        out[((size_t)b * NQH + h * GQA + g) * HD + d] = O / Lsel;
    }
}

extern "C" void kernel_launch(void* const* d_in, const int* in_sizes, int n_in,
                              void* d_out, int out_size, void* d_ws, size_t ws_size,
                              hipStream_t stream) {
    const float* q  = (const float*)d_in[0];
    const float* k  = (const float*)d_in[1];
    const float* v  = (const float*)d_in[2];
    const float* kc = (const float*)d_in[3];
    const float* vc = (const float*)d_in[4];
    const int*   bt = (const int*)d_in[5];
    int B  = in_sizes[0] / (NQH * HD);
    int nb = in_sizes[5] / B;
    int T  = nb * PBLK;

    float* out = (float*)d_out;
    paged_attn_kernel<<<B * NKVH, 512, 0, stream>>>(q, k, v, kc, vc, bt, out, T, nb);
}

// Round 13
// 127.114 us; speedup vs baseline: 1.3237x; 1.3237x over previous
//
#include <hip/hip_runtime.h>
#include <hip/hip_bf16.h>
#include <math.h>

#define HD    128
#define NQH   32
#define NKVH  8
#define GQA   4
#define PBLK  16
#define MAXNB 512
#define L2_10000 13.287712379549449f   // log2(10000)
#define NEGBIG (-1.0e9f)               // inf-free "minus infinity"

typedef float f4    __attribute__((ext_vector_type(4)));
typedef float f32x4 __attribute__((ext_vector_type(4)));
typedef short bf8   __attribute__((ext_vector_type(8)));   // 8 bf16 = 4 VGPR

// RNE f32->bf16 via compiler (m240: do NOT hand-write cvt_pk inline asm)
__device__ __forceinline__ bf8 pack8(const float* v) {
    union { __hip_bfloat16 h[8]; bf8 b; } t;
#pragma unroll
    for (int j = 0; j < 8; ++j) t.h[j] = __float2bfloat16(v[j]);
    return t.b;
}

// interleaved rope table: tab[t*128 + 2f] = cos(t*invf_f), +1 = sin
__global__ void rope_table_kernel(float* __restrict__ tab, int T) {
    int idx = blockIdx.x * blockDim.x + threadIdx.x;
    int total = (T + 1) * 64;
    if (idx >= total) return;
    int t = idx >> 6, f = idx & 63;
    float invf = exp2f(-(float)f * (L2_10000 / 64.0f));
    float ss, cc;
    sincosf((float)t * invf, &ss, &cc);
    tab[(size_t)t * 128 + 2 * f]     = cc;
    tab[(size_t)t * 128 + 2 * f + 1] = ss;
}

// MFMA flash-decode: per wave, 32-token units. Scores: S[16tok,16col(4 heads)]
// = mfma_16x16x32_bf16(A=K-tile, B=Q) x4 K-slices. PV: O[16row(4 heads),16dim]
// = mfma(A=P, B=V) per 16-dim col-tile.
__global__ __launch_bounds__(256) void paged_attn_kernel(
    const float* __restrict__ q,
    const float* __restrict__ kcur,
    const float* __restrict__ vcur,
    const float* __restrict__ kc,
    const float* __restrict__ vc,
    const int* __restrict__ bt,
    const float* __restrict__ tab,
    float* __restrict__ out,       // S==1
    float* __restrict__ pm,        // [nblk][4]
    float* __restrict__ pl,
    float* __restrict__ po,        // [nblk][4][HD]
    int T, int nb, int S, int useTable)
{
    const int bh  = blockIdx.x / S;
    const int sp  = blockIdx.x - bh * S;
    const int b   = bh >> 3, h = bh & 7;
    const int tid = threadIdx.x;
    const int w   = tid >> 6;       // wave 0..3
    const int l   = tid & 63;
    const int c   = l & 15;         // head col (scores/P) / dim-in-tile (V) / token-in-tile (K)
    const int u   = l >> 4;         // 0..3

    __shared__ int   sbt[MAXNB];
    __shared__ float qsm[4 * HD];
    __shared__ float smw[4][4], slw[4][4];
    __shared__ float sO[4][4][HD];

    const int* btrow = bt + (size_t)b * nb;
    for (int i = tid; i < nb && i < MAXNB; i += 256) sbt[i] = btrow[i];
    {   // rope current q (4 heads), fold in 128^-0.5
        const int g = tid >> 6, f = tid & 63;
        const float* qb = q + ((size_t)b * NQH + h * GQA + g) * HD;
        float xlo = qb[f], xhi = qb[64 + f];
        float cc, ss;
        if (useTable) { cc = tab[(size_t)T * 128 + 2 * f]; ss = tab[(size_t)T * 128 + 2 * f + 1]; }
        else { float invf = exp2f(-(float)f * (L2_10000 / 64.f)); sincosf((float)T * invf, &ss, &cc); }
        const float scale = 0.08838834764831845f;
        qsm[g * HD + f]      = (xlo * cc - xhi * ss) * scale;
        qsm[g * HD + 64 + f] = (xhi * cc + xlo * ss) * scale;
    }
    __syncthreads();
    const int* sbtp = (nb <= MAXNB) ? sbt : btrow;

    // Q B-frags: col=c (head, 0 for c>=4), k = u*8 + 32*s4 + j
    bf8 qf[4];
    {
        float tv[8];
#pragma unroll
        for (int s4 = 0; s4 < 4; ++s4) {
            const int db = u * 8 + 32 * s4;
#pragma unroll
            for (int j = 0; j < 8; ++j) tv[j] = (c < 4) ? qsm[c * HD + db + j] : 0.f;
            qf[s4] = pack8(tv);
        }
    }

    const int total = T + 1;
    const int chunk = (((total + S - 1) / S) + 31) & ~31;   // 32-aligned splits
    const int lo = sp * chunk;
    const int hi = min(lo + chunk, total);

    const float* kcurp = kcur + ((size_t)b * NKVH + h) * HD;
    const float* vcurp = vcur + ((size_t)b * NKVH + h) * HD;

    auto rowp = [&](int t, const float* cache, const float* curp) -> const float* {
        int tcl = min(t, T);
        if (tcl == T) return curp;
        int blk = sbtp[tcl >> 4];
        return cache + ((size_t)blk * PBLK + (tcl & 15)) * (NKVH * HD) + (size_t)h * HD;
    };

    float invfA[8], invfB[8];
    if (!useTable) {
#pragma unroll
        for (int j = 0; j < 8; ++j) {
            invfA[j] = exp2f(-(float)(u * 8 + j) * (L2_10000 / 64.f));
            invfB[j] = exp2f(-(float)(32 + u * 8 + j) * (L2_10000 / 64.f));
        }
    }

    float m_run = NEGBIG, l_run = 0.f;
    f32x4 o[8] = {};

    for (int tok0 = lo + w * 32; tok0 < hi; tok0 += 128) {
        const bool tail = (tok0 + 32 > hi);
        f32x4 sa = {0.f, 0.f, 0.f, 0.f}, sb = {0.f, 0.f, 0.f, 0.f};

#pragma unroll
        for (int tile = 0; tile < 2; ++tile) {
            const int tA  = tok0 + tile * 16 + c;    // this lane's K token (A row)
            const int tAc = min(tA, T);
            const float* kb = rowp(tA, kc, kcurp);
            f4 k0a = *(const f4*)(kb + u * 8);
            f4 k0b = *(const f4*)(kb + u * 8 + 4);
            f4 k1a = *(const f4*)(kb + 32 + u * 8);
            f4 k1b = *(const f4*)(kb + 32 + u * 8 + 4);
            f4 k2a = *(const f4*)(kb + 64 + u * 8);
            f4 k2b = *(const f4*)(kb + 64 + u * 8 + 4);
            f4 k3a = *(const f4*)(kb + 96 + u * 8);
            f4 k3b = *(const f4*)(kb + 96 + u * 8 + 4);
            float cs0[16], cs1[16];
            if (useTable) {
                const float* tb = tab + (size_t)tAc * 128;
#pragma unroll
                for (int i = 0; i < 4; ++i) {
                    f4 x = *(const f4*)(tb + u * 16 + 4 * i);
                    cs0[4 * i] = x.x; cs0[4 * i + 1] = x.y; cs0[4 * i + 2] = x.z; cs0[4 * i + 3] = x.w;
                    f4 y = *(const f4*)(tb + 64 + u * 16 + 4 * i);
                    cs1[4 * i] = y.x; cs1[4 * i + 1] = y.y; cs1[4 * i + 2] = y.z; cs1[4 * i + 3] = y.w;
                }
            } else {
#pragma unroll
                for (int j = 0; j < 8; ++j) {
                    sincosf((float)tAc * invfA[j], &cs0[2 * j + 1], &cs0[2 * j]);
                    sincosf((float)tAc * invfB[j], &cs1[2 * j + 1], &cs1[2 * j]);
                }
            }
            float lo0[8], lo1[8], hi0[8], hi1[8];
#pragma unroll
            for (int j = 0; j < 8; ++j) {
                float a0 = (j < 4) ? k0a[j] : k0b[j - 4];
                float h0 = (j < 4) ? k2a[j] : k2b[j - 4];
                float a1 = (j < 4) ? k1a[j] : k1b[j - 4];
                float h1 = (j < 4) ? k3a[j] : k3b[j - 4];
                float c0 = cs0[2 * j], s0 = cs0[2 * j + 1];
                float c1 = cs1[2 * j], s1 = cs1[2 * j + 1];
                lo0[j] = a0 * c0 - h0 * s0;  hi0[j] = h0 * c0 + a0 * s0;
                lo1[j] = a1 * c1 - h1 * s1;  hi1[j] = h1 * c1 + a1 * s1;
            }
            bf8 f0 = pack8(lo0), f1 = pack8(lo1), f2 = pack8(hi0), f3 = pack8(hi1);
            if (tile == 0) {
                sa = __builtin_amdgcn_mfma_f32_16x16x32_bf16(f0, qf[0], sa, 0, 0, 0);
                sa = __builtin_amdgcn_mfma_f32_16x16x32_bf16(f1, qf[1], sa, 0, 0, 0);
                sa = __builtin_amdgcn_mfma_f32_16x16x32_bf16(f2, qf[2], sa, 0, 0, 0);
                sa = __builtin_amdgcn_mfma_f32_16x16x32_bf16(f3, qf[3], sa, 0, 0, 0);
            } else {
                sb = __builtin_amdgcn_mfma_f32_16x16x32_bf16(f0, qf[0], sb, 0, 0, 0);
                sb = __builtin_amdgcn_mfma_f32_16x16x32_bf16(f1, qf[1], sb, 0, 0, 0);
                sb = __builtin_amdgcn_mfma_f32_16x16x32_bf16(f2, qf[2], sb, 0, 0, 0);
                sb = __builtin_amdgcn_mfma_f32_16x16x32_bf16(f3, qf[3], sb, 0, 0, 0);
            }
        }

        if (tail) {   // mask tokens >= hi (inf-free)
#pragma unroll
            for (int r = 0; r < 4; ++r) {
                if (tok0 + u * 4 + r      >= hi) sa[r] = NEGBIG;
                if (tok0 + 16 + u * 4 + r >= hi) sb[r] = NEGBIG;
            }
        }

        // ---- online softmax over the 32-token unit (per head col c) ----
        float mx = fmaxf(fmaxf(fmaxf(sa[0], sa[1]), fmaxf(sa[2], sa[3])),
                         fmaxf(fmaxf(sb[0], sb[1]), fmaxf(sb[2], sb[3])));
        mx = fmaxf(mx, __shfl_xor(mx, 16));
        mx = fmaxf(mx, __shfl_xor(mx, 32));
        float mn = fmaxf(m_run, mx);
        float e  = __expf(m_run - mn);
        float pA[4], pB[4];
#pragma unroll
        for (int r = 0; r < 4; ++r) { pA[r] = __expf(sa[r] - mn); pB[r] = __expf(sb[r] - mn); }
        float sum = pA[0] + pA[1] + pA[2] + pA[3] + pB[0] + pB[1] + pB[2] + pB[3];
        sum += __shfl_xor(sum, 16);
        sum += __shfl_xor(sum, 32);
        l_run = l_run * e + sum;
        m_run = mn;
        // broadcast per-head rescale to all lanes, scale O (reg r = head r)
        f32x4 ef;
        ef.x = __shfl(e, (l & 48) + 0);
        ef.y = __shfl(e, (l & 48) + 1);
        ef.z = __shfl(e, (l & 48) + 2);
        ef.w = __shfl(e, (l & 48) + 3);
#pragma unroll
        for (int ct = 0; ct < 8; ++ct) o[ct] *= ef;

        // ---- P A-frag: row=c(head), k=u*8+j (token-in-unit) ----
        float pv8[8];
#pragma unroll
        for (int j = 0; j < 8; ++j) {
            int idx = (((2 * u + (j >> 2)) & 3) << 4) + c;
            float va  = __shfl(pA[j & 3], idx);
            float vb2 = __shfl(pB[j & 3], idx);
            float v = (u < 2) ? va : vb2;
            pv8[j] = (c < 4) ? v : 0.f;
        }
        bf8 pf = pack8(pv8);

        // ---- V B-frags + PV mfma per 16-dim col tile ----
        const float* vr0 = rowp(tok0 + u * 8 + 0, vc, vcurp);
        const float* vr1 = rowp(tok0 + u * 8 + 1, vc, vcurp);
        const float* vr2 = rowp(tok0 + u * 8 + 2, vc, vcurp);
        const float* vr3 = rowp(tok0 + u * 8 + 3, vc, vcurp);
        const float* vr4 = rowp(tok0 + u * 8 + 4, vc, vcurp);
        const float* vr5 = rowp(tok0 + u * 8 + 5, vc, vcurp);
        const float* vr6 = rowp(tok0 + u * 8 + 6, vc, vcurp);
        const float* vr7 = rowp(tok0 + u * 8 + 7, vc, vcurp);
#pragma unroll
        for (int ct = 0; ct < 8; ++ct) {
            const int d = ct * 16 + c;
            float vv[8];
            vv[0] = vr0[d]; vv[1] = vr1[d]; vv[2] = vr2[d]; vv[3] = vr3[d];
            vv[4] = vr4[d]; vv[5] = vr5[d]; vv[6] = vr6[d]; vv[7] = vr7[d];
            bf8 vf = pack8(vv);
            o[ct] = __builtin_amdgcn_mfma_f32_16x16x32_bf16(pf, vf, o[ct], 0, 0, 0);
        }
    }

    // ---- cross-wave combine ----
    if (l < 4) { smw[w][l] = m_run; slw[w][l] = l_run; }
    if (u == 0) {
#pragma unroll
        for (int ct = 0; ct < 8; ++ct) {
            sO[w][0][ct * 16 + c] = o[ct].x;
            sO[w][1][ct * 16 + c] = o[ct].y;
            sO[w][2][ct * 16 + c] = o[ct].z;
            sO[w][3][ct * 16 + c] = o[ct].w;
        }
    }
    __syncthreads();
#pragma unroll
    for (int rep = 0; rep < 2; ++rep) {
        int i = tid + 256 * rep;         // over 4 heads x 128 dims
        int g = i >> 7, d = i & 127;
        float M = fmaxf(fmaxf(smw[0][g], smw[1][g]), fmaxf(smw[2][g], smw[3][g]));
        float L = 0.f, O = 0.f;
#pragma unroll
        for (int wv = 0; wv < 4; ++wv) {
            float wgt = __expf(smw[wv][g] - M);
            L += wgt * slw[wv][g];
            O += wgt * sO[wv][g][d];
        }
        if (S == 1) {
            out[(size_t)b * (NQH * HD) + (size_t)(h * GQA + g) * HD + d] = O / L;
        } else {
            int pidx = blockIdx.x * 4 + g;
            po[(size_t)pidx * HD + d] = O;
            if (d == 0) { pm[pidx] = M; pl[pidx] = L; }
        }
    }
}

__global__ void combine_kernel(
    const float* __restrict__ pm, const float* __restrict__ pl,
    const float* __restrict__ po, float* __restrict__ out, int S)
{
    int i = blockIdx.x * blockDim.x + threadIdx.x;   // over B*NQH*HD
    int d  = i & 127;
    int qh = (i >> 7) & 31;
    int b  = i >> 12;
    int h  = qh >> 2;
    int g  = qh & 3;
    int base = ((b * NKVH + h) * S) * 4 + g;
    float M = NEGBIG;
    for (int s = 0; s < S; ++s) M = fmaxf(M, pm[base + s * 4]);
    float L = 0.f, O = 0.f;
    for (int s = 0; s < S; ++s) {
        float wgt = __expf(pm[base + s * 4] - M);
        L += wgt * pl[base + s * 4];
        O += wgt * po[(size_t)(base + s * 4) * HD + d];
    }
    out[i] = O / L;
}

extern "C" void kernel_launch(void* const* d_in, const int* in_sizes, int n_in,
                              void* d_out, int out_size, void* d_ws, size_t ws_size,
                              hipStream_t stream) {
    const float* q  = (const float*)d_in[0];
    const float* k  = (const float*)d_in[1];
    const float* v  = (const float*)d_in[2];
    const float* kc = (const float*)d_in[3];
    const float* vc = (const float*)d_in[4];
    const int*   bt = (const int*)d_in[5];
    int B  = in_sizes[0] / (NQH * HD);
    int nb = in_sizes[5] / B;
    int T  = nb * PBLK;

    float* out = (float*)d_out;
    char*  ws  = (char*)d_ws;

    size_t tabBytes = (size_t)(T + 1) * 128 * sizeof(float);
    size_t off = (tabBytes + 255) & ~(size_t)255;

    int S = 4;
    int nblk = B * NKVH * S;
    size_t pmB = (size_t)nblk * 4 * sizeof(float);
    size_t poB = (size_t)nblk * 4 * HD * sizeof(float);
    size_t need = off + 2 * pmB + poB;

    int useTable = (ws_size >= tabBytes) ? 1 : 0;
    if (ws_size < need) S = 1;

    float* tab = (float*)ws;
    float* pm  = (float*)(ws + off);
    float* pl  = (float*)(ws + off + pmB);
    float* po  = (float*)(ws + off + 2 * pmB);

    if (useTable) {
        int tot = (T + 1) * 64;
        rope_table_kernel<<<(tot + 255) / 256, 256, 0, stream>>>(tab, T);
    }
    paged_attn_kernel<<<B * NKVH * S, 256, 0, stream>>>(
        q, k, v, kc, vc, bt, tab, out, pm, pl, po, T, nb, S, useTable);
    if (S > 1) {
        int totalOut = B * NQH * HD;
        combine_kernel<<<(totalOut + 255) / 256, 256, 0, stream>>>(pm, pl, po, out, S);
    }
}